// Round 3
// baseline (160.388 us; speedup 1.0000x reference)
//
#include <hip/hip_runtime.h>
#include <hip/hip_bf16.h>

// AngleProtoLoss: loss = -mean_n logsoftmax(clip(cos(last_n,cent_k),1e-6)*w+b)[n,n]
// Identity: loss_n = ln2*(log2(sum_k 2^{z_nk}) - z_nn), z = clamp(cos*w*log2e); b cancels.
// k1: centroids+norms -> unit cent (bf16), w*log2e-prescaled unit last (bf16), fp32 z_nn.
//     float4 loads (5x16B/lane): lanes<32 hold even-m rows, lanes>=32 odd-m rows.
// k2: bf16 MFMA 16x16x32, wave owns 64 rows (A in regs), B staged via global_load_lds
//     with XOR chunk swizzle into DOUBLE-BUFFERED LDS (one barrier/iter); grid (32,32)
//     = 1024 blocks @ 4 blocks/CU for latency hiding; epilogue native exp2, clamp in
//     exp domain via wave-uniform sign branch.
// k3: single block: loss = ln2/N * sum_n (log2(S_n) - z_nn).
// NOTE (R1 post-mortem): do NOT fuse k3 via per-block __threadfence()+ticket — the
// device-scope fence (buffer_wbl2/inv) per block serialized k2 to 73 us (all pipes idle).

typedef __attribute__((ext_vector_type(8))) short short8;
typedef __attribute__((ext_vector_type(4))) float f32x4;

#define NSPK 8192
#define DEMB 128
#define MUTT 10
#define LOG2E 1.44269504088896340736f
#define LN2   0.69314718055994530942f

// workspace: floats [0,8192) = zdiag, [8192,16384) = zsum; then bf16 matrices
#define WS_ZDIAG 0
#define WS_ZSUM  8192
#define WS_LASTB 65536      // byte offset, 2 MB
#define WS_CENTB 2162688    // byte offset, 2 MB

__global__ __launch_bounds__(256) void k1_prep(const float* __restrict__ x,
                                               const float* __restrict__ wp,
                                               float* __restrict__ W,
                                               __hip_bfloat16* __restrict__ lastb,
                                               __hip_bfloat16* __restrict__ centb) {
    const int wv = threadIdx.x >> 6;
    const int l  = threadIdx.x & 63;
    const int n  = blockIdx.x * 4 + wv;           // one wave per speaker
    if (blockIdx.x < 32) W[WS_ZSUM + blockIdx.x * 256 + threadIdx.x] = 0.f;

    // flat 1280 floats per speaker; lane l, step i -> float4 at 256*i + 4*l.
    // lanes 0..31: m = 2i, d = 4l..4l+3 ; lanes 32..63: m = 2i+1, d = 4(l-32)..
    const float4* xr = (const float4*)(x + (size_t)n * (MUTT * DEMB)) + l;
    float4 v[5];
#pragma unroll
    for (int i = 0; i < 5; ++i) v[i] = xr[i * 64];

    // centroid: this half's 5 rows, then add the other half's 5 rows via xor-32
    float4 cs;
    cs.x = ((v[0].x + v[1].x) + (v[2].x + v[3].x)) + v[4].x;
    cs.y = ((v[0].y + v[1].y) + (v[2].y + v[3].y)) + v[4].y;
    cs.z = ((v[0].z + v[1].z) + (v[2].z + v[3].z)) + v[4].z;
    cs.w = ((v[0].w + v[1].w) + (v[2].w + v[3].w)) + v[4].w;
    cs.x += __shfl_xor(cs.x, 32);
    cs.y += __shfl_xor(cs.y, 32);
    cs.z += __shfl_xor(cs.z, 32);
    cs.w += __shfl_xor(cs.w, 32);
    float4 cent;
    cent.x = cs.x * 0.1f; cent.y = cs.y * 0.1f; cent.z = cs.z * 0.1f; cent.w = cs.w * 0.1f;

    // last row (m=9) lives in v[4] of lanes >= 32; mirror it into lanes < 32
    float4 lv = v[4];
    {
        const float tx = __shfl_xor(lv.x, 32);
        const float ty = __shfl_xor(lv.y, 32);
        const float tz = __shfl_xor(lv.z, 32);
        const float tw = __shfl_xor(lv.w, 32);
        if (l < 32) { lv.x = tx; lv.y = ty; lv.z = tz; lv.w = tw; }
    }

    // both halves now hold identical dim-sets -> reduce within 32-lane half only
    float sl = lv.x * lv.x + lv.y * lv.y + lv.z * lv.z + lv.w * lv.w;
    float sc = cent.x * cent.x + cent.y * cent.y + cent.z * cent.z + cent.w * cent.w;
    float dp = lv.x * cent.x + lv.y * cent.y + lv.z * cent.z + lv.w * cent.w;
#pragma unroll
    for (int off = 1; off < 32; off <<= 1) {
        sl += __shfl_xor(sl, off);
        sc += __shfl_xor(sc, off);
        dp += __shfl_xor(dp, off);
    }
    const float il = rsqrtf(sl), ic = rsqrtf(sc);
    const float scale = wp[0] * LOG2E;
    const float as = il * scale;                  // prescale last by w*log2e

    // lanes<32 write prescaled-unit last, lanes>=32 write unit centroid (8B/lane)
    const float  f  = (l < 32) ? as : ic;
    const float4 s4 = (l < 32) ? lv : cent;
    __hip_bfloat16* bp = ((l < 32) ? lastb : centb) + (size_t)n * DEMB + 4 * (l & 31);
    union { __hip_bfloat162 h[2]; uint2 u; } pk;
    pk.h[0].x = __float2bfloat16(s4.x * f);
    pk.h[0].y = __float2bfloat16(s4.y * f);
    pk.h[1].x = __float2bfloat16(s4.z * f);
    pk.h[1].y = __float2bfloat16(s4.w * f);
    *(uint2*)bp = pk.u;

    if (l == 0) {
        const float lo = scale >= 0.f ? 1e-6f * scale : -INFINITY;
        const float hi = scale >= 0.f ? INFINITY : 1e-6f * scale;
        W[WS_ZDIAG + n] = fminf(fmaxf(dp * il * ic * scale, lo), hi);
    }
}

// grid (32,32): 256-row block x 256-col chunk. 4 waves; wave owns 64 rows (4 row-tiles).
// 1024 blocks -> 4 blocks/CU (LDS 32KB, VGPR<=128) for latency hiding.
__global__ __launch_bounds__(256, 4) void k2_main(
        const __hip_bfloat16* __restrict__ lastb,
        const __hip_bfloat16* __restrict__ centb,
        const float* __restrict__ wp,
        float* __restrict__ W) {
    const int tid  = threadIdx.x;
    const int lane = tid & 63;
    const int wv   = tid >> 6;
    const int quad = lane >> 4;
    const int l16  = lane & 15;
    const int R0   = blockIdx.x * 256;
    const int C0   = blockIdx.y * 256;
    const float scale = wp[0] * LOG2E;
    // clamp moved to exp domain (2^z monotone). scale>=0: e >= c0; scale<0: e <= c0.
    const float c0  = __builtin_amdgcn_exp2f(1e-6f * scale);
    const bool  pos = (scale >= 0.f);

    __shared__ uint4 Bs4[2048];   // 2 x 16 KB double buffer, XOR chunk-swizzled
    char* Bsc = (char*)Bs4;

    const int srow = wv * 16 + quad;          // staging row (+i*4)
    const int sp   = l16;                     // slot within row

    // prologue: DMA tile 0 into buf 0 (overlaps the A-frag loads below)
#pragma unroll
    for (int i = 0; i < 4; ++i) {
        const int row = srow + i * 4;
        const int c   = sp ^ (row & 15);
        const char* src = (const char*)centb + ((size_t)(C0 + row) << 8) + (c << 4);
        char* dst = Bsc + (wv * 4096 + i * 1024 + lane * 16);
        __builtin_amdgcn_global_load_lds(
            (const __attribute__((address_space(1))) unsigned int*)src,
            (__attribute__((address_space(3))) unsigned int*)dst, 16, 0, 0);
    }

    // A fragments (held whole kernel): rows R0 + wv*64 + rt*16 + l16, k = quad*8 + kc*32
    short8 a[4][4];
    {
        const short* ap = (const short*)lastb + (size_t)(R0 + wv * 64 + l16) * DEMB + quad * 8;
#pragma unroll
        for (int rt = 0; rt < 4; ++rt)
#pragma unroll
            for (int kc = 0; kc < 4; ++kc)
                a[rt][kc] = *(const short8*)(ap + rt * 16 * DEMB + kc * 32);
    }

    // swizzled B-fragment byte offsets within a 16-row ntile: row=l16, chunk=(quad+4kc)^l16
    int roff[4];
#pragma unroll
    for (int kc = 0; kc < 4; ++kc)
        roff[kc] = l16 * 256 + (((quad + 4 * kc) ^ l16) << 4);

    float racc[4][4] = {{0.f}};

    for (int it = 0; it < 4; ++it) {
        // drains vmcnt -> DMA(it) landed; also all waves done reading buf[(it+1)&1]
        __syncthreads();
        if (it < 3) {
            const int c0n = C0 + (it + 1) * 64;
            char* bufn = Bsc + ((it + 1) & 1) * 16384;
#pragma unroll
            for (int i = 0; i < 4; ++i) {
                const int row = srow + i * 4;
                const int c   = sp ^ (row & 15);
                const char* src = (const char*)centb + ((size_t)(c0n + row) << 8) + (c << 4);
                char* dst = bufn + (wv * 4096 + i * 1024 + lane * 16);
                __builtin_amdgcn_global_load_lds(
                    (const __attribute__((address_space(1))) unsigned int*)src,
                    (__attribute__((address_space(3))) unsigned int*)dst, 16, 0, 0);
            }
        }
        const char* buf = Bsc + (it & 1) * 16384;
#pragma unroll
        for (int nt = 0; nt < 4; ++nt) {
            short8 b[4];
#pragma unroll
            for (int kc = 0; kc < 4; ++kc)
                b[kc] = *(const short8*)(buf + nt * 4096 + roff[kc]);
            if (pos) {   // wave-uniform: single-sided clamp
#pragma unroll
                for (int rt = 0; rt < 4; ++rt) {
                    f32x4 acc = {0.f, 0.f, 0.f, 0.f};
#pragma unroll
                    for (int kc = 0; kc < 4; ++kc)
                        acc = __builtin_amdgcn_mfma_f32_16x16x32_bf16(a[rt][kc], b[kc], acc, 0, 0, 0);
#pragma unroll
                    for (int r = 0; r < 4; ++r)
                        racc[rt][r] += fmaxf(__builtin_amdgcn_exp2f(acc[r]), c0);
                }
            } else {
#pragma unroll
                for (int rt = 0; rt < 4; ++rt) {
                    f32x4 acc = {0.f, 0.f, 0.f, 0.f};
#pragma unroll
                    for (int kc = 0; kc < 4; ++kc)
                        acc = __builtin_amdgcn_mfma_f32_16x16x32_bf16(a[rt][kc], b[kc], acc, 0, 0, 0);
#pragma unroll
                    for (int r = 0; r < 4; ++r)
                        racc[rt][r] += fminf(__builtin_amdgcn_exp2f(acc[r]), c0);
                }
            }
        }
    }
    // reduce row sums over the 16 l16-lanes holding the same rows
#pragma unroll
    for (int off = 1; off < 16; off <<= 1)
#pragma unroll
        for (int rt = 0; rt < 4; ++rt)
#pragma unroll
            for (int r = 0; r < 4; ++r)
                racc[rt][r] += __shfl_xor(racc[rt][r], off);
    if (l16 == 0) {
#pragma unroll
        for (int rt = 0; rt < 4; ++rt)
#pragma unroll
            for (int r = 0; r < 4; ++r)
                atomicAdd(&W[WS_ZSUM + R0 + wv * 64 + rt * 16 + quad * 4 + r], racc[rt][r]);
    }
}

__global__ __launch_bounds__(256) void k3_loss(const float* __restrict__ W,
                                               float* __restrict__ out) {
    float v = 0.f;
    for (int n = threadIdx.x; n < NSPK; n += 256)
        v += __log2f(W[WS_ZSUM + n]) - W[WS_ZDIAG + n];
#pragma unroll
    for (int off = 1; off < 64; off <<= 1) v += __shfl_xor(v, off);
    __shared__ float red[4];
    if ((threadIdx.x & 63) == 0) red[threadIdx.x >> 6] = v;
    __syncthreads();
    if (threadIdx.x == 0)
        out[0] = (red[0] + red[1] + red[2] + red[3]) * (LN2 / (float)NSPK);
}

extern "C" void kernel_launch(void* const* d_in, const int* in_sizes, int n_in,
                              void* d_out, int out_size, void* d_ws, size_t ws_size,
                              hipStream_t stream) {
    const float* x = (const float*)d_in[0];
    const float* w = (const float*)d_in[1];
    // b (d_in[2]) cancels analytically — unused.
    float* W = (float*)d_ws;
    __hip_bfloat16* lastb = (__hip_bfloat16*)((char*)d_ws + WS_LASTB);
    __hip_bfloat16* centb = (__hip_bfloat16*)((char*)d_ws + WS_CENTB);

    k1_prep<<<NSPK / 4, 256, 0, stream>>>(x, w, W, lastb, centb);
    k2_main<<<dim3(32, 32), 256, 0, stream>>>(lastb, centb, w, W);
    k3_loss<<<1, 256, 0, stream>>>(W, (float*)d_out);
}

// Round 4
// 113.702 us; speedup vs baseline: 1.4106x; 1.4106x over previous
//
#include <hip/hip_runtime.h>
#include <hip/hip_bf16.h>

// AngleProtoLoss: loss = -mean_n logsoftmax(clip(cos(last_n,cent_k),1e-6)*w+b)[n,n]
// Identity: loss_n = ln2*(log2(sum_k 2^{z_nk}) - z_nn), z = clamp(cos*w*log2e); b cancels.
// k1: centroids+norms -> unit cent (bf16), w*log2e-prescaled unit last (bf16), fp32 z_nn.
//     float4 loads (5x16B/lane): lanes<32 hold even-m rows, lanes>=32 odd-m rows.
// k2: R0-proven structure: grid (32,16), 8 iters, lb(256,2). bf16 MFMA 16x16x32, wave
//     owns 64 rows (A in regs), B staged via global_load_lds + XOR chunk swizzle into
//     double-buffered LDS (one barrier/iter); epilogue native exp2, clamp in exp domain.
// k3: single block: loss = ln2/N * sum_n (log2(S_n) - z_nn).
// R1 post-mortem: per-block __threadfence()+ticket fusion serializes k2 to 73us (idle).
// R3 post-mortem: grid (32,32)/lb(256,4) thrashes XCD L2 (FETCH 9.3MB->103MB, k2 75us).
//     k2 locality is L2-capacity-critical: keep 512 blocks / 2 per CU.

typedef __attribute__((ext_vector_type(8))) short short8;
typedef __attribute__((ext_vector_type(4))) float f32x4;

#define NSPK 8192
#define DEMB 128
#define MUTT 10
#define LOG2E 1.44269504088896340736f
#define LN2   0.69314718055994530942f

// workspace: floats [0,8192) = zdiag, [8192,16384) = zsum; then bf16 matrices
#define WS_ZDIAG 0
#define WS_ZSUM  8192
#define WS_LASTB 65536      // byte offset, 2 MB
#define WS_CENTB 2162688    // byte offset, 2 MB

__global__ __launch_bounds__(256) void k1_prep(const float* __restrict__ x,
                                               const float* __restrict__ wp,
                                               float* __restrict__ W,
                                               __hip_bfloat16* __restrict__ lastb,
                                               __hip_bfloat16* __restrict__ centb) {
    const int wv = threadIdx.x >> 6;
    const int l  = threadIdx.x & 63;
    const int n  = blockIdx.x * 4 + wv;           // one wave per speaker
    if (blockIdx.x < 32) W[WS_ZSUM + blockIdx.x * 256 + threadIdx.x] = 0.f;

    // flat 1280 floats per speaker; lane l, step i -> float4 at 64*i + l.
    // lanes 0..31: m = 2i, d = 4l..4l+3 ; lanes 32..63: m = 2i+1, d = 4(l-32)..
    const float4* xr = (const float4*)(x + (size_t)n * (MUTT * DEMB)) + l;
    float4 v[5];
#pragma unroll
    for (int i = 0; i < 5; ++i) v[i] = xr[i * 64];

    // centroid: this half's 5 rows, then add the other half's 5 rows via xor-32
    float4 cs;
    cs.x = ((v[0].x + v[1].x) + (v[2].x + v[3].x)) + v[4].x;
    cs.y = ((v[0].y + v[1].y) + (v[2].y + v[3].y)) + v[4].y;
    cs.z = ((v[0].z + v[1].z) + (v[2].z + v[3].z)) + v[4].z;
    cs.w = ((v[0].w + v[1].w) + (v[2].w + v[3].w)) + v[4].w;
    cs.x += __shfl_xor(cs.x, 32);
    cs.y += __shfl_xor(cs.y, 32);
    cs.z += __shfl_xor(cs.z, 32);
    cs.w += __shfl_xor(cs.w, 32);
    float4 cent;
    cent.x = cs.x * 0.1f; cent.y = cs.y * 0.1f; cent.z = cs.z * 0.1f; cent.w = cs.w * 0.1f;

    // last row (m=9) lives in v[4] of lanes >= 32; mirror it into lanes < 32
    float4 lv = v[4];
    {
        const float tx = __shfl_xor(lv.x, 32);
        const float ty = __shfl_xor(lv.y, 32);
        const float tz = __shfl_xor(lv.z, 32);
        const float tw = __shfl_xor(lv.w, 32);
        if (l < 32) { lv.x = tx; lv.y = ty; lv.z = tz; lv.w = tw; }
    }

    // both halves now hold identical dim-sets -> reduce within 32-lane half only
    float sl = lv.x * lv.x + lv.y * lv.y + lv.z * lv.z + lv.w * lv.w;
    float sc = cent.x * cent.x + cent.y * cent.y + cent.z * cent.z + cent.w * cent.w;
    float dp = lv.x * cent.x + lv.y * cent.y + lv.z * cent.z + lv.w * cent.w;
#pragma unroll
    for (int off = 1; off < 32; off <<= 1) {
        sl += __shfl_xor(sl, off);
        sc += __shfl_xor(sc, off);
        dp += __shfl_xor(dp, off);
    }
    const float il = rsqrtf(sl), ic = rsqrtf(sc);
    const float scale = wp[0] * LOG2E;
    const float as = il * scale;                  // prescale last by w*log2e

    // lanes<32 write prescaled-unit last, lanes>=32 write unit centroid (8B/lane)
    const float  f  = (l < 32) ? as : ic;
    const float4 s4 = (l < 32) ? lv : cent;
    __hip_bfloat16* bp = ((l < 32) ? lastb : centb) + (size_t)n * DEMB + 4 * (l & 31);
    union { __hip_bfloat162 h[2]; uint2 u; } pk;
    pk.h[0].x = __float2bfloat16(s4.x * f);
    pk.h[0].y = __float2bfloat16(s4.y * f);
    pk.h[1].x = __float2bfloat16(s4.z * f);
    pk.h[1].y = __float2bfloat16(s4.w * f);
    *(uint2*)bp = pk.u;

    if (l == 0) {
        const float lo = scale >= 0.f ? 1e-6f * scale : -INFINITY;
        const float hi = scale >= 0.f ? INFINITY : 1e-6f * scale;
        W[WS_ZDIAG + n] = fminf(fmaxf(dp * il * ic * scale, lo), hi);
    }
}

// grid (32,16): 256-row block x 512-col chunk. 4 waves; wave owns 64 rows (4 row-tiles).
__global__ __launch_bounds__(256, 2) void k2_main(
        const __hip_bfloat16* __restrict__ lastb,
        const __hip_bfloat16* __restrict__ centb,
        const float* __restrict__ wp,
        float* __restrict__ W) {
    const int tid  = threadIdx.x;
    const int lane = tid & 63;
    const int wv   = tid >> 6;
    const int quad = lane >> 4;
    const int l16  = lane & 15;
    const int R0   = blockIdx.x * 256;
    const int C0   = blockIdx.y * 512;
    const float scale = wp[0] * LOG2E;
    // clamp moved to exp domain (2^z monotone): e in [elo, ehi]
    const float c0  = __builtin_amdgcn_exp2f(1e-6f * scale);
    const float elo = scale >= 0.f ? c0 : 0.f;
    const float ehi = scale >= 0.f ? INFINITY : c0;

    __shared__ uint4 Bs4[2048];   // 2 x 16 KB double buffer, XOR chunk-swizzled
    char* Bsc = (char*)Bs4;

    const int srow = wv * 16 + quad;          // staging row (+i*4)
    const int sp   = l16;                     // slot within row

    // prologue: DMA tile 0 into buf 0 (overlaps the A-frag loads below)
#pragma unroll
    for (int i = 0; i < 4; ++i) {
        const int row = srow + i * 4;
        const int c   = sp ^ (row & 15);
        const char* src = (const char*)centb + ((size_t)(C0 + row) << 8) + (c << 4);
        char* dst = Bsc + (wv * 4096 + i * 1024 + lane * 16);
        __builtin_amdgcn_global_load_lds(
            (const __attribute__((address_space(1))) unsigned int*)src,
            (__attribute__((address_space(3))) unsigned int*)dst, 16, 0, 0);
    }

    // A fragments (held whole kernel): rows R0 + wv*64 + rt*16 + l16, k = quad*8 + kc*32
    short8 a[4][4];
    {
        const short* ap = (const short*)lastb + (size_t)(R0 + wv * 64 + l16) * DEMB + quad * 8;
#pragma unroll
        for (int rt = 0; rt < 4; ++rt)
#pragma unroll
            for (int kc = 0; kc < 4; ++kc)
                a[rt][kc] = *(const short8*)(ap + rt * 16 * DEMB + kc * 32);
    }

    // swizzled B-fragment byte offsets within a 16-row ntile: row=l16, chunk=(quad+4kc)^l16
    int roff[4];
#pragma unroll
    for (int kc = 0; kc < 4; ++kc)
        roff[kc] = l16 * 256 + (((quad + 4 * kc) ^ l16) << 4);

    float racc[4][4] = {{0.f}};

    for (int it = 0; it < 8; ++it) {
        // drains vmcnt -> DMA(it) landed; also all waves done reading buf[(it+1)&1]
        __syncthreads();
        if (it < 7) {
            const int c0n = C0 + (it + 1) * 64;
            char* bufn = Bsc + ((it + 1) & 1) * 16384;
#pragma unroll
            for (int i = 0; i < 4; ++i) {
                const int row = srow + i * 4;
                const int c   = sp ^ (row & 15);
                const char* src = (const char*)centb + ((size_t)(c0n + row) << 8) + (c << 4);
                char* dst = bufn + (wv * 4096 + i * 1024 + lane * 16);
                __builtin_amdgcn_global_load_lds(
                    (const __attribute__((address_space(1))) unsigned int*)src,
                    (__attribute__((address_space(3))) unsigned int*)dst, 16, 0, 0);
            }
        }
        const char* buf = Bsc + (it & 1) * 16384;
#pragma unroll
        for (int nt = 0; nt < 4; ++nt) {
            short8 b[4];
#pragma unroll
            for (int kc = 0; kc < 4; ++kc)
                b[kc] = *(const short8*)(buf + nt * 4096 + roff[kc]);
#pragma unroll
            for (int rt = 0; rt < 4; ++rt) {
                f32x4 acc = {0.f, 0.f, 0.f, 0.f};
#pragma unroll
                for (int kc = 0; kc < 4; ++kc)
                    acc = __builtin_amdgcn_mfma_f32_16x16x32_bf16(a[rt][kc], b[kc], acc, 0, 0, 0);
                // C layout: col = l16, row = quad*4 + r; acc is already z (A prescaled)
#pragma unroll
                for (int r = 0; r < 4; ++r) {
                    const float e = __builtin_amdgcn_exp2f(acc[r]);
                    racc[rt][r] += fminf(fmaxf(e, elo), ehi);
                }
            }
        }
    }
    // reduce row sums over the 16 l16-lanes holding the same rows
#pragma unroll
    for (int off = 1; off < 16; off <<= 1)
#pragma unroll
        for (int rt = 0; rt < 4; ++rt)
#pragma unroll
            for (int r = 0; r < 4; ++r)
                racc[rt][r] += __shfl_xor(racc[rt][r], off);
    if (l16 == 0) {
#pragma unroll
        for (int rt = 0; rt < 4; ++rt)
#pragma unroll
            for (int r = 0; r < 4; ++r)
                atomicAdd(&W[WS_ZSUM + R0 + wv * 64 + rt * 16 + quad * 4 + r], racc[rt][r]);
    }
}

__global__ __launch_bounds__(256) void k3_loss(const float* __restrict__ W,
                                               float* __restrict__ out) {
    float v = 0.f;
    for (int n = threadIdx.x; n < NSPK; n += 256)
        v += __log2f(W[WS_ZSUM + n]) - W[WS_ZDIAG + n];
#pragma unroll
    for (int off = 1; off < 64; off <<= 1) v += __shfl_xor(v, off);
    __shared__ float red[4];
    if ((threadIdx.x & 63) == 0) red[threadIdx.x >> 6] = v;
    __syncthreads();
    if (threadIdx.x == 0)
        out[0] = (red[0] + red[1] + red[2] + red[3]) * (LN2 / (float)NSPK);
}

extern "C" void kernel_launch(void* const* d_in, const int* in_sizes, int n_in,
                              void* d_out, int out_size, void* d_ws, size_t ws_size,
                              hipStream_t stream) {
    const float* x = (const float*)d_in[0];
    const float* w = (const float*)d_in[1];
    // b (d_in[2]) cancels analytically — unused.
    float* W = (float*)d_ws;
    __hip_bfloat16* lastb = (__hip_bfloat16*)((char*)d_ws + WS_LASTB);
    __hip_bfloat16* centb = (__hip_bfloat16*)((char*)d_ws + WS_CENTB);

    k1_prep<<<NSPK / 4, 256, 0, stream>>>(x, w, W, lastb, centb);
    k2_main<<<dim3(32, 16), 256, 0, stream>>>(lastb, centb, w, W);
    k3_loss<<<1, 256, 0, stream>>>(W, (float*)d_out);
}

// Round 5
// 110.581 us; speedup vs baseline: 1.4504x; 1.0282x over previous
//
#include <hip/hip_runtime.h>
#include <hip/hip_bf16.h>

// AngleProtoLoss: loss = -mean_n logsoftmax(clip(cos(last_n,cent_k),1e-6)*w+b)[n,n]
// Identity: loss_n = ln2*(log2(sum_k 2^{z_nk}) - z_nn), z = clamp(cos*w*log2e); b cancels.
// k1: centroids+norms -> unit cent (bf16), w*log2e-prescaled unit last (bf16), fp32 z_nn.
// k2: grid (32,16) x 512 threads (8 waves): same 512 blocks / same L2 footprint as the
//     proven R0 structure, but 4 waves/SIMD (was 2) to hide dep-chain latency (R4 model:
//     heaviest pipe ~6us vs 34us measured => 72% stall at 2 waves/SIMD). Wave owns 32
//     rows; LDS image & XOR chunk swizzle byte-identical to R0 (staging remapped).
// k3: single block: loss = ln2/N * sum_n (log2(S_n) - z_nn).
// R1 post-mortem: per-block __threadfence()+ticket fusion serializes k2 to 73us (idle).
// R3 post-mortem: 1024 blocks thrashes XCD L2 (FETCH 9.3MB->103MB, k2 75us). Keep 512
//     blocks; scale waves-per-block, not blocks.

typedef __attribute__((ext_vector_type(8))) short short8;
typedef __attribute__((ext_vector_type(4))) float f32x4;

#define NSPK 8192
#define DEMB 128
#define MUTT 10
#define LOG2E 1.44269504088896340736f
#define LN2   0.69314718055994530942f

// workspace: floats [0,8192) = zdiag, [8192,16384) = zsum; then bf16 matrices
#define WS_ZDIAG 0
#define WS_ZSUM  8192
#define WS_LASTB 65536      // byte offset, 2 MB
#define WS_CENTB 2162688    // byte offset, 2 MB

__global__ __launch_bounds__(256) void k1_prep(const float* __restrict__ x,
                                               const float* __restrict__ wp,
                                               float* __restrict__ W,
                                               __hip_bfloat16* __restrict__ lastb,
                                               __hip_bfloat16* __restrict__ centb) {
    const int wv = threadIdx.x >> 6;
    const int l  = threadIdx.x & 63;
    const int n  = blockIdx.x * 4 + wv;           // one wave per speaker
    if (blockIdx.x < 32) W[WS_ZSUM + blockIdx.x * 256 + threadIdx.x] = 0.f;

    // flat 1280 floats per speaker; lane l, step i -> float4 at 64*i + l.
    // lanes 0..31: m = 2i, d = 4l..4l+3 ; lanes 32..63: m = 2i+1, d = 4(l-32)..
    const float4* xr = (const float4*)(x + (size_t)n * (MUTT * DEMB)) + l;
    float4 v[5];
#pragma unroll
    for (int i = 0; i < 5; ++i) v[i] = xr[i * 64];

    // centroid: this half's 5 rows, then add the other half's 5 rows via xor-32
    float4 cs;
    cs.x = ((v[0].x + v[1].x) + (v[2].x + v[3].x)) + v[4].x;
    cs.y = ((v[0].y + v[1].y) + (v[2].y + v[3].y)) + v[4].y;
    cs.z = ((v[0].z + v[1].z) + (v[2].z + v[3].z)) + v[4].z;
    cs.w = ((v[0].w + v[1].w) + (v[2].w + v[3].w)) + v[4].w;
    cs.x += __shfl_xor(cs.x, 32);
    cs.y += __shfl_xor(cs.y, 32);
    cs.z += __shfl_xor(cs.z, 32);
    cs.w += __shfl_xor(cs.w, 32);
    float4 cent;
    cent.x = cs.x * 0.1f; cent.y = cs.y * 0.1f; cent.z = cs.z * 0.1f; cent.w = cs.w * 0.1f;

    // last row (m=9) lives in v[4] of lanes >= 32; mirror it into lanes < 32
    float4 lv = v[4];
    {
        const float tx = __shfl_xor(lv.x, 32);
        const float ty = __shfl_xor(lv.y, 32);
        const float tz = __shfl_xor(lv.z, 32);
        const float tw = __shfl_xor(lv.w, 32);
        if (l < 32) { lv.x = tx; lv.y = ty; lv.z = tz; lv.w = tw; }
    }

    // both halves now hold identical dim-sets -> reduce within 32-lane half only
    float sl = lv.x * lv.x + lv.y * lv.y + lv.z * lv.z + lv.w * lv.w;
    float sc = cent.x * cent.x + cent.y * cent.y + cent.z * cent.z + cent.w * cent.w;
    float dp = lv.x * cent.x + lv.y * cent.y + lv.z * cent.z + lv.w * cent.w;
#pragma unroll
    for (int off = 1; off < 32; off <<= 1) {
        sl += __shfl_xor(sl, off);
        sc += __shfl_xor(sc, off);
        dp += __shfl_xor(dp, off);
    }
    const float il = rsqrtf(sl), ic = rsqrtf(sc);
    const float scale = wp[0] * LOG2E;
    const float as = il * scale;                  // prescale last by w*log2e

    // lanes<32 write prescaled-unit last, lanes>=32 write unit centroid (8B/lane)
    const float  f  = (l < 32) ? as : ic;
    const float4 s4 = (l < 32) ? lv : cent;
    __hip_bfloat16* bp = ((l < 32) ? lastb : centb) + (size_t)n * DEMB + 4 * (l & 31);
    union { __hip_bfloat162 h[2]; uint2 u; } pk;
    pk.h[0].x = __float2bfloat16(s4.x * f);
    pk.h[0].y = __float2bfloat16(s4.y * f);
    pk.h[1].x = __float2bfloat16(s4.z * f);
    pk.h[1].y = __float2bfloat16(s4.w * f);
    *(uint2*)bp = pk.u;

    if (l == 0) {
        const float lo = scale >= 0.f ? 1e-6f * scale : -INFINITY;
        const float hi = scale >= 0.f ? INFINITY : 1e-6f * scale;
        W[WS_ZDIAG + n] = fminf(fmaxf(dp * il * ic * scale, lo), hi);
    }
}

// grid (32,16) x 512 threads: 256-row block x 512-col chunk, 8 waves; wave owns 32 rows.
// LDS image identical to R0: row rr (0..63) of the iter's 64-col B slab at byte rr*256,
// 16B chunk slot s holds global chunk s ^ (rr & 15).
__global__ __launch_bounds__(512, 4) void k2_main(
        const __hip_bfloat16* __restrict__ lastb,
        const __hip_bfloat16* __restrict__ centb,
        const float* __restrict__ wp,
        float* __restrict__ W) {
    const int tid  = threadIdx.x;
    const int lane = tid & 63;
    const int wv   = tid >> 6;                // 0..7
    const int quad = lane >> 4;
    const int l16  = lane & 15;
    const int R0   = blockIdx.x * 256;
    const int C0   = blockIdx.y * 512;
    const float scale = wp[0] * LOG2E;
    // clamp moved to exp domain (2^z monotone): e in [elo, ehi]
    const float c0  = __builtin_amdgcn_exp2f(1e-6f * scale);
    const float elo = scale >= 0.f ? c0 : 0.f;
    const float ehi = scale >= 0.f ? INFINITY : c0;

    __shared__ uint4 Bs4[2048];   // 2 x 16 KB double buffer, XOR chunk-swizzled
    char* Bsc = (char*)Bs4;

    // staging: wave wv stages rows wv*8 + i*4 + quad (i=0,1); dst = rr*256 + lane-slot*16
    // (wave-uniform base + lane*16, as global_load_lds requires)
#pragma unroll
    for (int i = 0; i < 2; ++i) {
        const int rr = wv * 8 + i * 4 + quad;
        const int c  = l16 ^ (rr & 15);
        const char* src = (const char*)centb + ((size_t)(C0 + rr) << 8) + (c << 4);
        char* dst = Bsc + (wv * 2048 + i * 1024 + lane * 16);
        __builtin_amdgcn_global_load_lds(
            (const __attribute__((address_space(1))) unsigned int*)src,
            (__attribute__((address_space(3))) unsigned int*)dst, 16, 0, 0);
    }

    // A fragments (held whole kernel): rows R0 + wv*32 + rt*16 + l16, k = quad*8 + kc*32
    short8 a[2][4];
    {
        const short* ap = (const short*)lastb + (size_t)(R0 + wv * 32 + l16) * DEMB + quad * 8;
#pragma unroll
        for (int rt = 0; rt < 2; ++rt)
#pragma unroll
            for (int kc = 0; kc < 4; ++kc)
                a[rt][kc] = *(const short8*)(ap + rt * 16 * DEMB + kc * 32);
    }

    // swizzled B-fragment byte offsets within a 16-row ntile: row=l16, chunk=(quad+4kc)^l16
    int roff[4];
#pragma unroll
    for (int kc = 0; kc < 4; ++kc)
        roff[kc] = l16 * 256 + (((quad + 4 * kc) ^ l16) << 4);

    float racc[2][4] = {{0.f}};

    for (int it = 0; it < 8; ++it) {
        // drains vmcnt -> DMA(it) landed; also all waves done reading buf[(it+1)&1]
        __syncthreads();
        if (it < 7) {
            const int c0n = C0 + (it + 1) * 64;
            char* bufn = Bsc + ((it + 1) & 1) * 16384;
#pragma unroll
            for (int i = 0; i < 2; ++i) {
                const int rr = wv * 8 + i * 4 + quad;
                const int c  = l16 ^ (rr & 15);
                const char* src = (const char*)centb + ((size_t)(c0n + rr) << 8) + (c << 4);
                char* dst = bufn + (wv * 2048 + i * 1024 + lane * 16);
                __builtin_amdgcn_global_load_lds(
                    (const __attribute__((address_space(1))) unsigned int*)src,
                    (__attribute__((address_space(3))) unsigned int*)dst, 16, 0, 0);
            }
        }
        const char* buf = Bsc + (it & 1) * 16384;
#pragma unroll
        for (int nt = 0; nt < 4; ++nt) {
            short8 b[4];
#pragma unroll
            for (int kc = 0; kc < 4; ++kc)
                b[kc] = *(const short8*)(buf + nt * 4096 + roff[kc]);
#pragma unroll
            for (int rt = 0; rt < 2; ++rt) {
                f32x4 acc = {0.f, 0.f, 0.f, 0.f};
#pragma unroll
                for (int kc = 0; kc < 4; ++kc)
                    acc = __builtin_amdgcn_mfma_f32_16x16x32_bf16(a[rt][kc], b[kc], acc, 0, 0, 0);
                // C layout: col = l16, row = quad*4 + r; acc is already z (A prescaled)
#pragma unroll
                for (int r = 0; r < 4; ++r) {
                    const float e = __builtin_amdgcn_exp2f(acc[r]);
                    racc[rt][r] += fminf(fmaxf(e, elo), ehi);
                }
            }
        }
    }
    // reduce row sums over the 16 l16-lanes holding the same rows
#pragma unroll
    for (int off = 1; off < 16; off <<= 1)
#pragma unroll
        for (int rt = 0; rt < 2; ++rt)
#pragma unroll
            for (int r = 0; r < 4; ++r)
                racc[rt][r] += __shfl_xor(racc[rt][r], off);
    if (l16 == 0) {
#pragma unroll
        for (int rt = 0; rt < 2; ++rt)
#pragma unroll
            for (int r = 0; r < 4; ++r)
                atomicAdd(&W[WS_ZSUM + R0 + wv * 32 + rt * 16 + quad * 4 + r], racc[rt][r]);
    }
}

__global__ __launch_bounds__(256) void k3_loss(const float* __restrict__ W,
                                               float* __restrict__ out) {
    float v = 0.f;
    for (int n = threadIdx.x; n < NSPK; n += 256)
        v += __log2f(W[WS_ZSUM + n]) - W[WS_ZDIAG + n];
#pragma unroll
    for (int off = 1; off < 64; off <<= 1) v += __shfl_xor(v, off);
    __shared__ float red[4];
    if ((threadIdx.x & 63) == 0) red[threadIdx.x >> 6] = v;
    __syncthreads();
    if (threadIdx.x == 0)
        out[0] = (red[0] + red[1] + red[2] + red[3]) * (LN2 / (float)NSPK);
}

extern "C" void kernel_launch(void* const* d_in, const int* in_sizes, int n_in,
                              void* d_out, int out_size, void* d_ws, size_t ws_size,
                              hipStream_t stream) {
    const float* x = (const float*)d_in[0];
    const float* w = (const float*)d_in[1];
    // b (d_in[2]) cancels analytically — unused.
    float* W = (float*)d_ws;
    __hip_bfloat16* lastb = (__hip_bfloat16*)((char*)d_ws + WS_LASTB);
    __hip_bfloat16* centb = (__hip_bfloat16*)((char*)d_ws + WS_CENTB);

    k1_prep<<<NSPK / 4, 256, 0, stream>>>(x, w, W, lastb, centb);
    k2_main<<<dim3(32, 16), 512, 0, stream>>>(lastb, centb, w, W);
    k3_loss<<<1, 256, 0, stream>>>(W, (float*)d_out);
}